// Round 8
// baseline (141.903 us; speedup 1.0000x reference)
//
#include <hip/hip_runtime.h>
#include <stdint.h>

typedef __bf16 v8bf __attribute__((ext_vector_type(8)));
typedef float  v4f  __attribute__((ext_vector_type(4)));

__device__ __forceinline__ uint16_t f2bf(float f){
  union { float f; uint32_t u; } v; v.f = f;
  uint32_t r = v.u + 0x7FFFu + ((v.u >> 16) & 1u);
  return (uint16_t)(r >> 16);
}
__device__ __forceinline__ float bf2f(uint16_t u){
  union { uint32_t u; float f; } v; v.u = ((uint32_t)u) << 16; return v.f;
}
__device__ __forceinline__ v4f vzero(){ v4f z = {0.f,0.f,0.f,0.f}; return z; }

// async global->LDS, 16B per lane; LDS dest is wave-uniform base + lane*16
__device__ __forceinline__ void gld16(const uint16_t* __restrict__ g, uint16_t* l){
  __builtin_amdgcn_global_load_lds((const __attribute__((address_space(1))) void*)g,
                                   (__attribute__((address_space(3))) void*)l, 16, 0, 0);
}

// ---- 64x64 bf16 tile staging, LDS row stride 72 (colsum/vprep) ----
__device__ __forceinline__ void ld64(uint4 r[2], const uint16_t* __restrict__ g, int ldg, int tid){
  int row = tid >> 2, c = (tid & 3) * 16;
  r[0] = *(const uint4*)(g + (size_t)row * ldg + c);
  r[1] = *(const uint4*)(g + (size_t)row * ldg + c + 8);
}
__device__ __forceinline__ void st64(uint16_t* __restrict__ s, const uint4 r[2], int tid){
  int row = tid >> 2, c = (tid & 3) * 16;
  *(uint4*)(s + row * 72 + c) = r[0];
  *(uint4*)(s + row * 72 + c + 8) = r[1];
}
__device__ __forceinline__ void stage64(uint16_t* s, const uint16_t* g, int ldg, int tid){
  uint4 r[2]; ld64(r, g, ldg, tid); st64(s, r, tid);
}

// ---- 64x64 bf16 tile staging, LINEAR stride 64 + chunk-XOR swizzle (attnout) ----
// logical 16B chunk c of row r lives at physical chunk c ^ (r&7)
__device__ __forceinline__ void st64s(uint16_t* __restrict__ s, const uint4 r[2], int tid){
  int row = tid >> 2, c0 = (tid & 3) * 2, sw = row & 7;
  *(uint4*)(s + row * 64 + ((c0 ^ sw) * 8))       = r[0];
  *(uint4*)(s + row * 64 + (((c0 + 1) ^ sw) * 8)) = r[1];
}
__device__ __forceinline__ void stage64s(uint16_t* s, const uint16_t* g, int ldg, int tid){
  uint4 r[2]; ld64(r, g, ldg, tid); st64s(s, r, tid);
}

// ---------------- prep ----------------
__global__ void k_xcast(const float* __restrict__ X, uint16_t* __restrict__ Xb){
  int i = (blockIdx.x * 256 + threadIdx.x) * 8;
  float4 a = *(const float4*)(X + i);
  float4 b = *(const float4*)(X + i + 4);
  union { uint16_t h[8]; uint4 v; } o;
  o.h[0]=f2bf(a.x); o.h[1]=f2bf(a.y); o.h[2]=f2bf(a.z); o.h[3]=f2bf(a.w);
  o.h[4]=f2bf(b.x); o.h[5]=f2bf(b.y); o.h[6]=f2bf(b.z); o.h[7]=f2bf(b.w);
  *(uint4*)(Xb + i) = o.v;
}

__global__ void k_zero(float* __restrict__ p){
  int i = (blockIdx.x * 256 + threadIdx.x) * 4;
  *(float4*)(p + i) = make_float4(0.f, 0.f, 0.f, 0.f);
}

__global__ void k_weff(const float* __restrict__ Wq, const float* __restrict__ Aq, const float* __restrict__ Bq,
                       const float* __restrict__ Wk, const float* __restrict__ Ak, const float* __restrict__ Bk,
                       const float* __restrict__ Wv, const float* __restrict__ Av, const float* __restrict__ Bv,
                       uint16_t* __restrict__ Wo){
  int y = blockIdx.y;
  const float* W  = (y == 0) ? Wq : (y == 1) ? Wk : Wv;
  const float* A  = (y == 0) ? Aq : (y == 1) ? Ak : Av;
  const float* Bm = (y == 0) ? Bq : (y == 1) ? Bk : Bv;
  int idx = blockIdx.x * 256 + threadIdx.x;
  int f = idx >> 10, k = idx & 1023;
  float acc = W[idx];
  #pragma unroll
  for (int r = 0; r < 16; ++r) acc += Bm[f * 16 + r] * A[r * 1024 + k];
  Wo[(size_t)y * 1048576 + idx] = f2bf(acc);
}

// ---------------- fused QKV projection GEMM (m97 structure + XOR swizzle) ----------------
__global__ __launch_bounds__(256, 4)
void k_gemm(const uint16_t* __restrict__ Ag, const uint16_t* __restrict__ Bg,
            const float* __restrict__ qb, const float* __restrict__ kb,
            const float* __restrict__ vb, uint16_t* __restrict__ Cg){
  __shared__ __align__(16) uint16_t smem[16896];   // As[8192] Bs[8192]; reused as Ct[128*132]
  uint16_t* As = smem;
  uint16_t* Bs = smem + 8192;
  int tid = threadIdx.x, lane = tid & 63, wid = tid >> 6;
  int l15 = lane & 15, lg = lane >> 4;
  int wr = wid >> 1, wc = wid & 1;
  int bid = blockIdx.x, xcd = bid & 7, idx = bid >> 3;
  int nb = xcd * 96 + idx;                 // 768 blocks, 96/XCD chunk
  int mt = nb / 24, nt = nb - mt * 24;
  int m0 = mt * 128, n0 = nt * 128;

  int lr  = lane >> 3;                          // 0..7
  int lcs = (((lane & 7) ^ lr)) * 8;            // inverse-swizzled global col (elems)
  const uint16_t* Abase = Ag + (size_t)(m0 + wid * 32 + lr) * 1024 + lcs;
  const uint16_t* Bbase = Bg + (size_t)(n0 + wid * 32 + lr) * 1024 + lcs;
  uint16_t* Alds = As + wid * 32 * 64;
  uint16_t* Blds = Bs + wid * 32 * 64;

  int sw = l15 & 7;

  v4f acc[4][4];
  #pragma unroll
  for (int a = 0; a < 4; ++a)
    #pragma unroll
    for (int c = 0; c < 4; ++c) acc[a][c] = vzero();

  for (int kk = 0; kk < 1024; kk += 64){
    __syncthreads();
    #pragma unroll
    for (int i = 0; i < 4; ++i){
      gld16(Abase + (size_t)(i * 8) * 1024 + kk, Alds + i * 8 * 64);
      gld16(Bbase + (size_t)(i * 8) * 1024 + kk, Blds + i * 8 * 64);
    }
    __syncthreads();
    #pragma unroll
    for (int kc = 0; kc < 2; ++kc){
      v8bf af[4], bfr[4];
      int cs = ((kc * 4 + lg) ^ sw) * 8;
      #pragma unroll
      for (int mi = 0; mi < 4; ++mi)
        af[mi] = *(const v8bf*)(As + (wr * 64 + mi * 16 + l15) * 64 + cs);
      #pragma unroll
      for (int nj = 0; nj < 4; ++nj)
        bfr[nj] = *(const v8bf*)(Bs + (wc * 64 + nj * 16 + l15) * 64 + cs);
      #pragma unroll
      for (int mi = 0; mi < 4; ++mi)
        #pragma unroll
        for (int nj = 0; nj < 4; ++nj)
          acc[mi][nj] = __builtin_amdgcn_mfma_f32_16x16x32_bf16(af[mi], bfr[nj], acc[mi][nj], 0, 0, 0);
    }
  }
  __syncthreads();
  uint16_t* Ct = smem;
  #pragma unroll
  for (int nj = 0; nj < 4; ++nj){
    int n = n0 + wc * 64 + nj * 16 + l15;
    float bv_ = (n < 1024) ? qb[n] : (n < 2048) ? kb[n - 1024] : vb[n - 2048];
    #pragma unroll
    for (int mi = 0; mi < 4; ++mi)
      #pragma unroll
      for (int r = 0; r < 4; ++r){
        int ml = wr * 64 + mi * 16 + lg * 4 + r;
        Ct[ml * 132 + wc * 64 + nj * 16 + l15] = f2bf(acc[mi][nj][r] + bv_);
      }
  }
  __syncthreads();
  {
    int row = tid >> 1;
    int c0  = (tid & 1) * 64;
    uint16_t* gp = Cg + (size_t)(m0 + row) * 3072 + n0 + c0;
    const uint16_t* sp = Ct + row * 132 + c0;
    #pragma unroll
    for (int c = 0; c < 8; ++c)
      *(uint4*)(gp + c * 8) = *(const uint4*)(sp + c * 8);
  }
}

// ---------------- pass 1: column sums (pair of j-tiles, i-range split by parity) ----------------
__global__ __launch_bounds__(256, 4)
void k_colsum(const uint16_t* __restrict__ QKVg, float* __restrict__ csum){
  __shared__ __align__(16) uint16_t Ka[64 * 72], KbS[64 * 72], Qs[64 * 72];
  __shared__ float colacc[128];
  int tid = threadIdx.x, lane = tid & 63, l15 = lane & 15, lg = lane >> 4, wid = tid >> 6;
  int wr = wid >> 1, wc = wid & 1;
  int bid = blockIdx.x, xcd = bid & 7, idx = bid >> 3;
  int bh = xcd * 8 + (idx & 7);
  int rest = idx >> 3;
  int pr = rest & 7, ph = rest >> 3;
  int b = bh >> 4, h = bh & 15;
  int jtA = pr, jtB = 15 - pr;
  const uint16_t* Qb = QKVg + (size_t)b * 1024 * 3072 + h * 64;
  const uint16_t* Kb = QKVg + (size_t)b * 1024 * 3072 + 1024 + h * 64;
  stage64(Ka,  Kb + (size_t)jtA * 64 * 3072, 3072, tid);
  stage64(KbS, Kb + (size_t)jtB * 64 * 3072, 3072, tid);
  if (tid < 128) colacc[tid] = 0.f;
  int it0 = jtA + ph;
  uint4 rq[2]; ld64(rq, Qb + (size_t)it0 * 64 * 3072, 3072, tid);
  float cpA[2] = {0.f, 0.f}, cpB[2] = {0.f, 0.f};
  for (int it = it0; it < 16; it += 2){
    __syncthreads();
    st64(Qs, rq, tid);
    __syncthreads();
    if (it + 2 < 16) ld64(rq, Qb + (size_t)(it + 2) * 64 * 3072, 3072, tid);
    bool doB = (it >= jtB);
    v4f sa[2][2], sb[2][2];
    #pragma unroll
    for (int a = 0; a < 2; ++a)
      #pragma unroll
      for (int c = 0; c < 2; ++c){ sa[a][c] = vzero(); sb[a][c] = vzero(); }
    #pragma unroll
    for (int kc = 0; kc < 2; ++kc){
      v8bf aq[2], k1[2], k2[2];
      #pragma unroll
      for (int mi = 0; mi < 2; ++mi)
        aq[mi] = *(const v8bf*)(Qs + (wr * 32 + mi * 16 + l15) * 72 + kc * 32 + lg * 8);
      #pragma unroll
      for (int nj = 0; nj < 2; ++nj)
        k1[nj] = *(const v8bf*)(Ka + (wc * 32 + nj * 16 + l15) * 72 + kc * 32 + lg * 8);
      #pragma unroll
      for (int mi = 0; mi < 2; ++mi)
        #pragma unroll
        for (int nj = 0; nj < 2; ++nj)
          sa[mi][nj] = __builtin_amdgcn_mfma_f32_16x16x32_bf16(aq[mi], k1[nj], sa[mi][nj], 0, 0, 0);
      if (doB){
        #pragma unroll
        for (int nj = 0; nj < 2; ++nj)
          k2[nj] = *(const v8bf*)(KbS + (wc * 32 + nj * 16 + l15) * 72 + kc * 32 + lg * 8);
        #pragma unroll
        for (int mi = 0; mi < 2; ++mi)
          #pragma unroll
          for (int nj = 0; nj < 2; ++nj)
            sb[mi][nj] = __builtin_amdgcn_mfma_f32_16x16x32_bf16(aq[mi], k2[nj], sb[mi][nj], 0, 0, 0);
      }
    }
    #pragma unroll
    for (int mi = 0; mi < 2; ++mi)
      #pragma unroll
      for (int nj = 0; nj < 2; ++nj)
        #pragma unroll
        for (int r = 0; r < 4; ++r){
          int il = wr * 32 + mi * 16 + lg * 4 + r;
          int jl = wc * 32 + nj * 16 + l15;
          if (it > jtA || il >= jl) cpA[nj] += __expf(sa[mi][nj][r] * 0.03125f);
          if (doB && (it > jtB || il >= jl)) cpB[nj] += __expf(sb[mi][nj][r] * 0.03125f);
        }
  }
  #pragma unroll
  for (int nj = 0; nj < 2; ++nj){
    float v = cpA[nj];
    v += __shfl_xor(v, 16, 64); v += __shfl_xor(v, 32, 64);
    if (lane < 16) atomicAdd(&colacc[wc * 32 + nj * 16 + l15], v);
    float w = cpB[nj];
    w += __shfl_xor(w, 16, 64); w += __shfl_xor(w, 32, 64);
    if (lane < 16) atomicAdd(&colacc[64 + wc * 32 + nj * 16 + l15], w);
  }
  __syncthreads();
  if (tid < 64)       atomicAdd(&csum[(size_t)bh * 1024 + jtA * 64 + tid], colacc[tid]);
  else if (tid < 128) atomicAdd(&csum[(size_t)bh * 1024 + jtB * 64 + (tid - 64)], colacc[tid]);
}

// ---------------- V' = V * mask/colsum, transposed to [bh][64 d][1024 j] ----------------
__global__ __launch_bounds__(256)
void k_vprep(const uint16_t* __restrict__ QKVg, const float* __restrict__ csum,
             const float* __restrict__ mask, uint16_t* __restrict__ Vp){
  __shared__ __align__(16) uint16_t Vs[128 * 72];
  __shared__ float scb[128];
  int tid = threadIdx.x;
  int bid = blockIdx.x, xcd = bid & 7, idx = bid >> 3;
  int bh = xcd * 8 + (idx & 7);
  int jt = idx >> 3;
  int b = bh >> 4, h = bh & 15;
  int j0 = jt * 128;
  stage64(Vs,           QKVg + ((size_t)(b * 1024 + j0)) * 3072 + 2048 + h * 64, 3072, tid);
  stage64(Vs + 64 * 72, QKVg + ((size_t)(b * 1024 + j0 + 64)) * 3072 + 2048 + h * 64, 3072, tid);
  if (tid < 128) scb[tid] = mask[b * 1024 + j0 + tid] / csum[(size_t)bh * 1024 + j0 + tid];
  __syncthreads();
  int d = tid >> 2, jc = (tid & 3) * 32;
  #pragma unroll
  for (int g8 = 0; g8 < 4; ++g8){
    union { uint16_t h[8]; uint4 v; } o;
    #pragma unroll
    for (int e = 0; e < 8; ++e){
      int j = jc + g8 * 8 + e;
      o.h[e] = f2bf(bf2f(Vs[j * 72 + d]) * scb[j]);
    }
    *(uint4*)(Vp + (size_t)bh * 65536 + (size_t)d * 1024 + j0 + jc + g8 * 8) = o.v;
  }
}

// ---------------- pass 2: O = exp(S) @ V', one 64-row i-tile per block ----------------
// grid 1024 = (xcd, bh, it); 32 KB LDS; coalesced LDS-staged O write
__global__ __launch_bounds__(256, 5)
void k_attnout(const uint16_t* __restrict__ QKVg, const uint16_t* __restrict__ Vp,
               float* __restrict__ out){
  __shared__ __align__(16) uint16_t smem[16384];   // Qs|Ks|Vt|Ps (64x64 each); reused as Of[64][68] f32
  uint16_t* Qs = smem;
  uint16_t* Ks = smem + 4096;
  uint16_t* Vt = smem + 8192;
  uint16_t* Ps = smem + 12288;
  int tid = threadIdx.x, lane = tid & 63, l15 = lane & 15, lg = lane >> 4, wid = tid >> 6;
  int wr = wid >> 1, wc = wid & 1;
  int sw = l15 & 7;                       // fragment-row swizzle key (row&7 == l15&7 everywhere)
  int bid = blockIdx.x, xcd = bid & 7, idx = bid >> 3;
  int bh = xcd * 8 + (idx & 7);
  int it = idx >> 3;                      // 0..15
  int b = bh >> 4, h = bh & 15;
  const uint16_t* Qb = QKVg + (size_t)b * 1024 * 3072 + h * 64;
  const uint16_t* Kb = QKVg + (size_t)b * 1024 * 3072 + 1024 + h * 64;
  const uint16_t* Vb = Vp + (size_t)bh * 65536;
  stage64s(Qs, Qb + (size_t)it * 64 * 3072, 3072, tid);
  uint4 rk[2], rv[2];
  ld64(rk, Kb, 3072, tid);
  ld64(rv, Vb, 1024, tid);
  v4f oacc[4];
  #pragma unroll
  for (int c = 0; c < 4; ++c) oacc[c] = vzero();

  for (int jt = 0; jt <= it; ++jt){
    __syncthreads();                      // prev PV done reading Ks/Vt/Ps
    st64s(Ks, rk, tid);
    st64s(Vt, rv, tid);
    __syncthreads();                      // staged tiles visible
    if (jt < it){
      ld64(rk, Kb + (size_t)(jt + 1) * 64 * 3072, 3072, tid);
      ld64(rv, Vb + (jt + 1) * 64, 1024, tid);
    }
    // QK^T: A=K rows (j), B=Q rows (i) -> C col=i(l15), row=j(lg*4+r)
    v4f sacc[2][2];
    #pragma unroll
    for (int a = 0; a < 2; ++a)
      #pragma unroll
      for (int c = 0; c < 2; ++c) sacc[a][c] = vzero();
    #pragma unroll
    for (int kc = 0; kc < 2; ++kc){
      v8bf ak[2], aq[2];
      int cs = ((kc * 4 + lg) ^ sw) * 8;
      #pragma unroll
      for (int mj = 0; mj < 2; ++mj)
        ak[mj] = *(const v8bf*)(Ks + (wr * 32 + mj * 16 + l15) * 64 + cs);
      #pragma unroll
      for (int ni = 0; ni < 2; ++ni)
        aq[ni] = *(const v8bf*)(Qs + (wc * 32 + ni * 16 + l15) * 64 + cs);
      __builtin_amdgcn_s_setprio(1);
      #pragma unroll
      for (int mj = 0; mj < 2; ++mj)
        #pragma unroll
        for (int ni = 0; ni < 2; ++ni)
          sacc[mj][ni] = __builtin_amdgcn_mfma_f32_16x16x32_bf16(ak[mj], aq[ni], sacc[mj][ni], 0, 0, 0);
      __builtin_amdgcn_s_setprio(0);
    }
    bool diag = (jt == it);
    #pragma unroll
    for (int mj = 0; mj < 2; ++mj)
      #pragma unroll
      for (int ni = 0; ni < 2; ++ni){
        int iL = wc * 32 + ni * 16 + l15;
        int jb = wr * 32 + mj * 16 + lg * 4;
        float e0 = (!diag || jb + 0 <= iL) ? __expf(sacc[mj][ni][0] * 0.03125f) : 0.f;
        float e1 = (!diag || jb + 1 <= iL) ? __expf(sacc[mj][ni][1] * 0.03125f) : 0.f;
        float e2 = (!diag || jb + 2 <= iL) ? __expf(sacc[mj][ni][2] * 0.03125f) : 0.f;
        float e3 = (!diag || jb + 3 <= iL) ? __expf(sacc[mj][ni][3] * 0.03125f) : 0.f;
        uint2 pk;
        pk.x = (uint32_t)f2bf(e0) | ((uint32_t)f2bf(e1) << 16);
        pk.y = (uint32_t)f2bf(e2) | ((uint32_t)f2bf(e3) << 16);
        int off = iL * 64 + (((jb >> 3) ^ (iL & 7)) * 8) + (jb & 7);
        *(uint2*)(Ps + off) = pk;
      }
    __syncthreads();                      // Ps visible
    // PV: warp w owns out rows [w*16, w*16+16); A=P rows(i), B=Vt rows(d)
    #pragma unroll
    for (int kc = 0; kc < 2; ++kc){
      v8bf pa, vb_[4];
      int csP = ((kc * 4 + lg) ^ ((wid * 16 + l15) & 7)) * 8;
      int cs  = ((kc * 4 + lg) ^ sw) * 8;
      pa = *(const v8bf*)(Ps + (wid * 16 + l15) * 64 + csP);
      #pragma unroll
      for (int nj = 0; nj < 4; ++nj)
        vb_[nj] = *(const v8bf*)(Vt + (nj * 16 + l15) * 64 + cs);
      __builtin_amdgcn_s_setprio(1);
      #pragma unroll
      for (int nj = 0; nj < 4; ++nj)
        oacc[nj] = __builtin_amdgcn_mfma_f32_16x16x32_bf16(pa, vb_[nj], oacc[nj], 0, 0, 0);
      __builtin_amdgcn_s_setprio(0);
    }
  }
  // ---- epilogue: stage O tile in LDS (f32, stride 68), store coalesced 64B/lane ----
  __syncthreads();                        // done with Qs/Ks/Vt/Ps
  float* Of = (float*)smem;               // 64*68*4 = 17408 B
  #pragma unroll
  for (int nj = 0; nj < 4; ++nj)
    #pragma unroll
    for (int r = 0; r < 4; ++r)
      Of[(wid * 16 + lg * 4 + r) * 68 + nj * 16 + l15] = oacc[nj][r];
  __syncthreads();
  {
    int row = tid >> 2, c0 = (tid & 3) * 16;
    float* gp = out + ((size_t)(b * 1024) + it * 64 + row) * 1024 + h * 64 + c0;
    const float* sp = Of + row * 68 + c0;
    #pragma unroll
    for (int c = 0; c < 4; ++c)
      *(float4*)(gp + c * 4) = *(const float4*)(sp + c * 4);
  }
}

extern "C" void kernel_launch(void* const* d_in, const int* in_sizes, int n_in,
                              void* d_out, int out_size, void* d_ws, size_t ws_size,
                              hipStream_t stream) {
  (void)in_sizes; (void)n_in; (void)out_size; (void)ws_size;
  const float* X    = (const float*)d_in[0];
  const float* mask = (const float*)d_in[1];
  const float* Wq   = (const float*)d_in[2];
  const float* bq   = (const float*)d_in[3];
  const float* Wk   = (const float*)d_in[4];
  const float* bk   = (const float*)d_in[5];
  const float* Wv   = (const float*)d_in[6];
  const float* bv   = (const float*)d_in[7];
  const float* Aq   = (const float*)d_in[8];
  const float* Bq   = (const float*)d_in[9];
  const float* Ak   = (const float*)d_in[10];
  const float* Bk   = (const float*)d_in[11];
  const float* Av   = (const float*)d_in[12];
  const float* Bv   = (const float*)d_in[13];
  float* out = (float*)d_out;

  uint16_t* Xb   = (uint16_t*)d_ws;                        // 8 MB
  uint16_t* Weff = Xb + (size_t)4096 * 1024;               // 6 MB  [3072][1024]
  uint16_t* QKV  = Weff + (size_t)3 * 1024 * 1024;         // 24 MB [4096][3072]
  uint16_t* Vp   = QKV + (size_t)4096 * 3072;              // 8 MB  [64][64][1024]
  float*    csum = (float*)(Vp + (size_t)64 * 64 * 1024);  // 256 KB

  k_xcast<<<2048, 256, 0, stream>>>(X, Xb);
  k_zero<<<64, 256, 0, stream>>>(csum);
  k_weff<<<dim3(4096, 3), 256, 0, stream>>>(Wq, Aq, Bq, Wk, Ak, Bk, Wv, Av, Bv, Weff);
  k_gemm<<<768, 256, 0, stream>>>(Xb, Weff, bq, bk, bv, QKV);
  k_colsum<<<1024, 256, 0, stream>>>(QKV, csum);
  k_vprep<<<512, 256, 0, stream>>>(QKV, csum, mask, Vp);
  k_attnout<<<1024, 256, 0, stream>>>(QKV, Vp, out);
}

// Round 9
// 128.622 us; speedup vs baseline: 1.1033x; 1.1033x over previous
//
#include <hip/hip_runtime.h>
#include <stdint.h>

typedef __bf16 v8bf __attribute__((ext_vector_type(8)));
typedef float  v4f  __attribute__((ext_vector_type(4)));

__device__ __forceinline__ uint16_t f2bf(float f){
  union { float f; uint32_t u; } v; v.f = f;
  uint32_t r = v.u + 0x7FFFu + ((v.u >> 16) & 1u);
  return (uint16_t)(r >> 16);
}
__device__ __forceinline__ float bf2f(uint16_t u){
  union { uint32_t u; float f; } v; v.u = ((uint32_t)u) << 16; return v.f;
}
__device__ __forceinline__ v4f vzero(){ v4f z = {0.f,0.f,0.f,0.f}; return z; }

// async global->LDS, 16B per lane; LDS dest is wave-uniform base + lane*16
__device__ __forceinline__ void gld16(const uint16_t* __restrict__ g, uint16_t* l){
  __builtin_amdgcn_global_load_lds((const __attribute__((address_space(1))) void*)g,
                                   (__attribute__((address_space(3))) void*)l, 16, 0, 0);
}

// ---- 64x64 bf16 tile staging, LDS row stride 72 (colsum/vprep) ----
__device__ __forceinline__ void ld64(uint4 r[2], const uint16_t* __restrict__ g, int ldg, int tid){
  int row = tid >> 2, c = (tid & 3) * 16;
  r[0] = *(const uint4*)(g + (size_t)row * ldg + c);
  r[1] = *(const uint4*)(g + (size_t)row * ldg + c + 8);
}
__device__ __forceinline__ void st64(uint16_t* __restrict__ s, const uint4 r[2], int tid){
  int row = tid >> 2, c = (tid & 3) * 16;
  *(uint4*)(s + row * 72 + c) = r[0];
  *(uint4*)(s + row * 72 + c + 8) = r[1];
}
__device__ __forceinline__ void stage64(uint16_t* s, const uint16_t* g, int ldg, int tid){
  uint4 r[2]; ld64(r, g, ldg, tid); st64(s, r, tid);
}

// ---- 64x64 bf16 tile staging, LINEAR stride 64 + chunk-XOR swizzle (attnout) ----
// logical 16B chunk c of row r lives at physical chunk c ^ (r&7)
__device__ __forceinline__ void st64s(uint16_t* __restrict__ s, const uint4 r[2], int tid){
  int row = tid >> 2, c0 = (tid & 3) * 2, sw = row & 7;
  *(uint4*)(s + row * 64 + ((c0 ^ sw) * 8))       = r[0];
  *(uint4*)(s + row * 64 + (((c0 + 1) ^ sw) * 8)) = r[1];
}
__device__ __forceinline__ void stage64s(uint16_t* s, const uint16_t* g, int ldg, int tid){
  uint4 r[2]; ld64(r, g, ldg, tid); st64s(s, r, tid);
}

// ---------------- prep ----------------
__global__ void k_xcast(const float* __restrict__ X, uint16_t* __restrict__ Xb){
  int i = (blockIdx.x * 256 + threadIdx.x) * 8;
  float4 a = *(const float4*)(X + i);
  float4 b = *(const float4*)(X + i + 4);
  union { uint16_t h[8]; uint4 v; } o;
  o.h[0]=f2bf(a.x); o.h[1]=f2bf(a.y); o.h[2]=f2bf(a.z); o.h[3]=f2bf(a.w);
  o.h[4]=f2bf(b.x); o.h[5]=f2bf(b.y); o.h[6]=f2bf(b.z); o.h[7]=f2bf(b.w);
  *(uint4*)(Xb + i) = o.v;
}

__global__ void k_zero(float* __restrict__ p){
  int i = (blockIdx.x * 256 + threadIdx.x) * 4;
  *(float4*)(p + i) = make_float4(0.f, 0.f, 0.f, 0.f);
}

__global__ void k_weff(const float* __restrict__ Wq, const float* __restrict__ Aq, const float* __restrict__ Bq,
                       const float* __restrict__ Wk, const float* __restrict__ Ak, const float* __restrict__ Bk,
                       const float* __restrict__ Wv, const float* __restrict__ Av, const float* __restrict__ Bv,
                       uint16_t* __restrict__ Wo){
  int y = blockIdx.y;
  const float* W  = (y == 0) ? Wq : (y == 1) ? Wk : Wv;
  const float* A  = (y == 0) ? Aq : (y == 1) ? Ak : Av;
  const float* Bm = (y == 0) ? Bq : (y == 1) ? Bk : Bv;
  int idx = blockIdx.x * 256 + threadIdx.x;
  int f = idx >> 10, k = idx & 1023;
  float acc = W[idx];
  #pragma unroll
  for (int r = 0; r < 16; ++r) acc += Bm[f * 16 + r] * A[r * 1024 + k];
  Wo[(size_t)y * 1048576 + idx] = f2bf(acc);
}

// ---------------- fused QKV projection GEMM (m97 structure + XOR swizzle) ----------------
__global__ __launch_bounds__(256, 4)
void k_gemm(const uint16_t* __restrict__ Ag, const uint16_t* __restrict__ Bg,
            const float* __restrict__ qb, const float* __restrict__ kb,
            const float* __restrict__ vb, uint16_t* __restrict__ Cg){
  __shared__ __align__(16) uint16_t smem[16896];   // As[8192] Bs[8192]; reused as Ct[128*132]
  uint16_t* As = smem;
  uint16_t* Bs = smem + 8192;
  int tid = threadIdx.x, lane = tid & 63, wid = tid >> 6;
  int l15 = lane & 15, lg = lane >> 4;
  int wr = wid >> 1, wc = wid & 1;
  int bid = blockIdx.x, xcd = bid & 7, idx = bid >> 3;
  int nb = xcd * 96 + idx;                 // 768 blocks, 96/XCD chunk
  int mt = nb / 24, nt = nb - mt * 24;
  int m0 = mt * 128, n0 = nt * 128;

  int lr  = lane >> 3;                          // 0..7
  int lcs = (((lane & 7) ^ lr)) * 8;            // inverse-swizzled global col (elems)
  const uint16_t* Abase = Ag + (size_t)(m0 + wid * 32 + lr) * 1024 + lcs;
  const uint16_t* Bbase = Bg + (size_t)(n0 + wid * 32 + lr) * 1024 + lcs;
  uint16_t* Alds = As + wid * 32 * 64;
  uint16_t* Blds = Bs + wid * 32 * 64;

  int sw = l15 & 7;

  v4f acc[4][4];
  #pragma unroll
  for (int a = 0; a < 4; ++a)
    #pragma unroll
    for (int c = 0; c < 4; ++c) acc[a][c] = vzero();

  for (int kk = 0; kk < 1024; kk += 64){
    __syncthreads();
    #pragma unroll
    for (int i = 0; i < 4; ++i){
      gld16(Abase + (size_t)(i * 8) * 1024 + kk, Alds + i * 8 * 64);
      gld16(Bbase + (size_t)(i * 8) * 1024 + kk, Blds + i * 8 * 64);
    }
    __syncthreads();
    #pragma unroll
    for (int kc = 0; kc < 2; ++kc){
      v8bf af[4], bfr[4];
      int cs = ((kc * 4 + lg) ^ sw) * 8;
      #pragma unroll
      for (int mi = 0; mi < 4; ++mi)
        af[mi] = *(const v8bf*)(As + (wr * 64 + mi * 16 + l15) * 64 + cs);
      #pragma unroll
      for (int nj = 0; nj < 4; ++nj)
        bfr[nj] = *(const v8bf*)(Bs + (wc * 64 + nj * 16 + l15) * 64 + cs);
      #pragma unroll
      for (int mi = 0; mi < 4; ++mi)
        #pragma unroll
        for (int nj = 0; nj < 4; ++nj)
          acc[mi][nj] = __builtin_amdgcn_mfma_f32_16x16x32_bf16(af[mi], bfr[nj], acc[mi][nj], 0, 0, 0);
    }
  }
  __syncthreads();
  uint16_t* Ct = smem;
  #pragma unroll
  for (int nj = 0; nj < 4; ++nj){
    int n = n0 + wc * 64 + nj * 16 + l15;
    float bv_ = (n < 1024) ? qb[n] : (n < 2048) ? kb[n - 1024] : vb[n - 2048];
    #pragma unroll
    for (int mi = 0; mi < 4; ++mi)
      #pragma unroll
      for (int r = 0; r < 4; ++r){
        int ml = wr * 64 + mi * 16 + lg * 4 + r;
        Ct[ml * 132 + wc * 64 + nj * 16 + l15] = f2bf(acc[mi][nj][r] + bv_);
      }
  }
  __syncthreads();
  {
    int row = tid >> 1;
    int c0  = (tid & 1) * 64;
    uint16_t* gp = Cg + (size_t)(m0 + row) * 3072 + n0 + c0;
    const uint16_t* sp = Ct + row * 132 + c0;
    #pragma unroll
    for (int c = 0; c < 8; ++c)
      *(uint4*)(gp + c * 8) = *(const uint4*)(sp + c * 8);
  }
}

// ---------------- pass 1: column sums (pair of j-tiles, i-range split by parity) ----------------
__global__ __launch_bounds__(256, 4)
void k_colsum(const uint16_t* __restrict__ QKVg, float* __restrict__ csum){
  __shared__ __align__(16) uint16_t Ka[64 * 72], KbS[64 * 72], Qs[64 * 72];
  __shared__ float colacc[128];
  int tid = threadIdx.x, lane = tid & 63, l15 = lane & 15, lg = lane >> 4, wid = tid >> 6;
  int wr = wid >> 1, wc = wid & 1;
  int bid = blockIdx.x, xcd = bid & 7, idx = bid >> 3;
  int bh = xcd * 8 + (idx & 7);
  int rest = idx >> 3;
  int pr = rest & 7, ph = rest >> 3;
  int b = bh >> 4, h = bh & 15;
  int jtA = pr, jtB = 15 - pr;
  const uint16_t* Qb = QKVg + (size_t)b * 1024 * 3072 + h * 64;
  const uint16_t* Kb = QKVg + (size_t)b * 1024 * 3072 + 1024 + h * 64;
  stage64(Ka,  Kb + (size_t)jtA * 64 * 3072, 3072, tid);
  stage64(KbS, Kb + (size_t)jtB * 64 * 3072, 3072, tid);
  if (tid < 128) colacc[tid] = 0.f;
  int it0 = jtA + ph;
  uint4 rq[2]; ld64(rq, Qb + (size_t)it0 * 64 * 3072, 3072, tid);
  float cpA[2] = {0.f, 0.f}, cpB[2] = {0.f, 0.f};
  for (int it = it0; it < 16; it += 2){
    __syncthreads();
    st64(Qs, rq, tid);
    __syncthreads();
    if (it + 2 < 16) ld64(rq, Qb + (size_t)(it + 2) * 64 * 3072, 3072, tid);
    bool doB = (it >= jtB);
    v4f sa[2][2], sb[2][2];
    #pragma unroll
    for (int a = 0; a < 2; ++a)
      #pragma unroll
      for (int c = 0; c < 2; ++c){ sa[a][c] = vzero(); sb[a][c] = vzero(); }
    #pragma unroll
    for (int kc = 0; kc < 2; ++kc){
      v8bf aq[2], k1[2], k2[2];
      #pragma unroll
      for (int mi = 0; mi < 2; ++mi)
        aq[mi] = *(const v8bf*)(Qs + (wr * 32 + mi * 16 + l15) * 72 + kc * 32 + lg * 8);
      #pragma unroll
      for (int nj = 0; nj < 2; ++nj)
        k1[nj] = *(const v8bf*)(Ka + (wc * 32 + nj * 16 + l15) * 72 + kc * 32 + lg * 8);
      #pragma unroll
      for (int mi = 0; mi < 2; ++mi)
        #pragma unroll
        for (int nj = 0; nj < 2; ++nj)
          sa[mi][nj] = __builtin_amdgcn_mfma_f32_16x16x32_bf16(aq[mi], k1[nj], sa[mi][nj], 0, 0, 0);
      if (doB){
        #pragma unroll
        for (int nj = 0; nj < 2; ++nj)
          k2[nj] = *(const v8bf*)(KbS + (wc * 32 + nj * 16 + l15) * 72 + kc * 32 + lg * 8);
        #pragma unroll
        for (int mi = 0; mi < 2; ++mi)
          #pragma unroll
          for (int nj = 0; nj < 2; ++nj)
            sb[mi][nj] = __builtin_amdgcn_mfma_f32_16x16x32_bf16(aq[mi], k2[nj], sb[mi][nj], 0, 0, 0);
      }
    }
    #pragma unroll
    for (int mi = 0; mi < 2; ++mi)
      #pragma unroll
      for (int nj = 0; nj < 2; ++nj)
        #pragma unroll
        for (int r = 0; r < 4; ++r){
          int il = wr * 32 + mi * 16 + lg * 4 + r;
          int jl = wc * 32 + nj * 16 + l15;
          if (it > jtA || il >= jl) cpA[nj] += __expf(sa[mi][nj][r] * 0.03125f);
          if (doB && (it > jtB || il >= jl)) cpB[nj] += __expf(sb[mi][nj][r] * 0.03125f);
        }
  }
  #pragma unroll
  for (int nj = 0; nj < 2; ++nj){
    float v = cpA[nj];
    v += __shfl_xor(v, 16, 64); v += __shfl_xor(v, 32, 64);
    if (lane < 16) atomicAdd(&colacc[wc * 32 + nj * 16 + l15], v);
    float w = cpB[nj];
    w += __shfl_xor(w, 16, 64); w += __shfl_xor(w, 32, 64);
    if (lane < 16) atomicAdd(&colacc[64 + wc * 32 + nj * 16 + l15], w);
  }
  __syncthreads();
  if (tid < 64)       atomicAdd(&csum[(size_t)bh * 1024 + jtA * 64 + tid], colacc[tid]);
  else if (tid < 128) atomicAdd(&csum[(size_t)bh * 1024 + jtB * 64 + (tid - 64)], colacc[tid]);
}

// ---------------- V' = V * mask/colsum, transposed to [bh][64 d][1024 j] ----------------
__global__ __launch_bounds__(256)
void k_vprep(const uint16_t* __restrict__ QKVg, const float* __restrict__ csum,
             const float* __restrict__ mask, uint16_t* __restrict__ Vp){
  __shared__ __align__(16) uint16_t Vs[128 * 72];
  __shared__ float scb[128];
  int tid = threadIdx.x;
  int bid = blockIdx.x, xcd = bid & 7, idx = bid >> 3;
  int bh = xcd * 8 + (idx & 7);
  int jt = idx >> 3;
  int b = bh >> 4, h = bh & 15;
  int j0 = jt * 128;
  stage64(Vs,           QKVg + ((size_t)(b * 1024 + j0)) * 3072 + 2048 + h * 64, 3072, tid);
  stage64(Vs + 64 * 72, QKVg + ((size_t)(b * 1024 + j0 + 64)) * 3072 + 2048 + h * 64, 3072, tid);
  if (tid < 128) scb[tid] = mask[b * 1024 + j0 + tid] / csum[(size_t)bh * 1024 + j0 + tid];
  __syncthreads();
  int d = tid >> 2, jc = (tid & 3) * 32;
  #pragma unroll
  for (int g8 = 0; g8 < 4; ++g8){
    union { uint16_t h[8]; uint4 v; } o;
    #pragma unroll
    for (int e = 0; e < 8; ++e){
      int j = jc + g8 * 8 + e;
      o.h[e] = f2bf(bf2f(Vs[j * 72 + d]) * scb[j]);
    }
    *(uint4*)(Vp + (size_t)bh * 65536 + (size_t)d * 1024 + j0 + jc + g8 * 8) = o.v;
  }
}

// ---------------- pass 2: O = exp(S) @ V', register-P, balanced pair of i-tiles ----------------
// grid 512 = (xcd, bh, pair). Warp (wr,wc): QK block j in wr*32-range, i in wc*32-range.
// P stays in registers; shfl redistributes C-frag (4 j/lane) -> A-frag (8 j/lane).
// Each warp accumulates partial O over its j-range; epilogue merges wr=0/wr=1 in LDS.
__global__ __launch_bounds__(256, 2)
void k_attnout(const uint16_t* __restrict__ QKVg, const uint16_t* __restrict__ Vp,
               float* __restrict__ out){
  __shared__ __align__(16) uint16_t smem[24576];  // Qs[0..8192) Ks[8192..12288) Vt[12288..16384) elems
  uint16_t* Qs = smem;                            // epilogue alias: Of f32[0..4352), Of2 f32[4352..8704)
  uint16_t* Ks = smem + 8192;
  uint16_t* Vt = smem + 12288;
  int tid = threadIdx.x, lane = tid & 63, l15 = lane & 15, lg = lane >> 4, wid = tid >> 6;
  int wr = wid >> 1, wc = wid & 1;
  int sw = l15 & 7;
  int bid = blockIdx.x, xcd = bid & 7, idx = bid >> 3;
  int bh = xcd * 8 + (idx & 7);
  int p4 = idx >> 3; int pr = (p4 < 4) ? p4 : 11 - p4;
  int b = bh >> 4, h = bh & 15;
  int itA = pr, itB = 15 - pr;
  const uint16_t* Qb = QKVg + (size_t)b * 1024 * 3072 + h * 64;
  const uint16_t* Kb = QKVg + (size_t)b * 1024 * 3072 + 1024 + h * 64;
  const uint16_t* Vb = Vp + (size_t)bh * 65536;
  stage64s(Qs,           Qb + (size_t)itA * 64 * 3072, 3072, tid);
  stage64s(Qs + 64 * 64, Qb + (size_t)itB * 64 * 3072, 3072, tid);
  uint4 rk[2], rv[2];
  ld64(rk, Kb, 3072, tid);
  ld64(rv, Vb, 1024, tid);
  // partial O: [half][ni(i16)][dj(d16)]; this warp's j-range only
  v4f oacc[2][2][4];
  #pragma unroll
  for (int a = 0; a < 2; ++a)
    #pragma unroll
    for (int c = 0; c < 2; ++c)
      #pragma unroll
      for (int d = 0; d < 4; ++d) oacc[a][c][d] = vzero();

  for (int jt = 0; jt <= itB; ++jt){
    __syncthreads();                    // prev tile's reads done
    st64s(Ks, rk, tid);
    st64s(Vt, rv, tid);
    __syncthreads();                    // staged tiles visible
    if (jt < itB){
      ld64(rk, Kb + (size_t)(jt + 1) * 64 * 3072, 3072, tid);
      ld64(rv, Vb + (jt + 1) * 64, 1024, tid);
    }
    // hoisted K and V fragments (shared by both halves)
    v8bf ak[2][2], vbf[4];              // ak[kc][mj]; vbf[dj]
    #pragma unroll
    for (int kc = 0; kc < 2; ++kc){
      int cs = ((kc * 4 + lg) ^ sw) * 8;
      #pragma unroll
      for (int mj = 0; mj < 2; ++mj)
        ak[kc][mj] = *(const v8bf*)(Ks + (wr * 32 + mj * 16 + l15) * 64 + cs);
    }
    {
      int csv = ((wr * 4 + lg) ^ sw) * 8;   // k-window = this warp's j-range
      #pragma unroll
      for (int dj = 0; dj < 4; ++dj)
        vbf[dj] = *(const v8bf*)(Vt + (dj * 16 + l15) * 64 + csv);
    }
    #pragma unroll
    for (int half = 0; half < 2; ++half){
      int ith = half ? itB : itA;
      if (jt <= ith){
        // QK^T: C col=i(l15), row=j(lg*4+r)
        v4f sacc[2][2];
        #pragma unroll
        for (int a = 0; a < 2; ++a)
          #pragma unroll
          for (int c = 0; c < 2; ++c) sacc[a][c] = vzero();
        #pragma unroll
        for (int kc = 0; kc < 2; ++kc){
          v8bf aq[2];
          int cs = ((kc * 4 + lg) ^ sw) * 8;
          #pragma unroll
          for (int ni = 0; ni < 2; ++ni)
            aq[ni] = *(const v8bf*)(Qs + (half * 64 + wc * 32 + ni * 16 + l15) * 64 + cs);
          __builtin_amdgcn_s_setprio(1);
          #pragma unroll
          for (int mj = 0; mj < 2; ++mj)
            #pragma unroll
            for (int ni = 0; ni < 2; ++ni)
              sacc[mj][ni] = __builtin_amdgcn_mfma_f32_16x16x32_bf16(ak[kc][mj], aq[ni], sacc[mj][ni], 0, 0, 0);
          __builtin_amdgcn_s_setprio(0);
        }
        // exp + causal mask + pack to bf16 pairs (register P)
        bool diag = (jt == ith);
        uint32_t pk[2][2][2];           // [mj][ni][word]
        #pragma unroll
        for (int mj = 0; mj < 2; ++mj)
          #pragma unroll
          for (int ni = 0; ni < 2; ++ni){
            int iL = wc * 32 + ni * 16 + l15;
            int jb = wr * 32 + mj * 16 + lg * 4;
            float e0 = (!diag || jb + 0 <= iL) ? __expf(sacc[mj][ni][0] * 0.03125f) : 0.f;
            float e1 = (!diag || jb + 1 <= iL) ? __expf(sacc[mj][ni][1] * 0.03125f) : 0.f;
            float e2 = (!diag || jb + 2 <= iL) ? __expf(sacc[mj][ni][2] * 0.03125f) : 0.f;
            float e3 = (!diag || jb + 3 <= iL) ? __expf(sacc[mj][ni][3] * 0.03125f) : 0.f;
            pk[mj][ni][0] = (uint32_t)f2bf(e0) | ((uint32_t)f2bf(e1) << 16);
            pk[mj][ni][1] = (uint32_t)f2bf(e2) | ((uint32_t)f2bf(e3) << 16);
          }
        // redistribute to A-frag: dst lane (l15,lg) needs P[i=*+l15][j = wr*32 + lg*8 + 0..7]
        int s0 = ((lg & 1) * 32) + l15;   // src lane: lg_s = (lg&1)*2
        int s1 = s0 + 16;                 // lg_s = (lg&1)*2 + 1
        bool hi = (lg >> 1) != 0;         // mj select
        #pragma unroll
        for (int ni = 0; ni < 2; ++ni){
          uint32_t a0x = __shfl((int)pk[0][ni][0], s0, 64), a1x = __shfl((int)pk[1][ni][0], s0, 64);
          uint32_t a0y = __shfl((int)pk[0][ni][1], s0, 64), a1y = __shfl((int)pk[1][ni][1], s0, 64);
          uint32_t b0x = __shfl((int)pk[0][ni][0], s1, 64), b1x = __shfl((int)pk[1][ni][0], s1, 64);
          uint32_t b0y = __shfl((int)pk[0][ni][1], s1, 64), b1y = __shfl((int)pk[1][ni][1], s1, 64);
          union { uint32_t u[4]; v8bf v; } fr;
          fr.u[0] = hi ? a1x : a0x;
          fr.u[1] = hi ? a1y : a0y;
          fr.u[2] = hi ? b1x : b0x;
          fr.u[3] = hi ? b1y : b0y;
          __builtin_amdgcn_s_setprio(1);
          #pragma unroll
          for (int dj = 0; dj < 4; ++dj)
            oacc[half][ni][dj] = __builtin_amdgcn_mfma_f32_16x16x32_bf16(fr.v, vbf[dj], oacc[half][ni][dj], 0, 0, 0);
          __builtin_amdgcn_s_setprio(0);
        }
      }
    }
  }
  // ---- epilogue: merge wr=0/wr=1 partials in LDS, coalesced f32 store ----
  #pragma unroll
  for (int half = 0; half < 2; ++half){
    int ith = half ? itB : itA;
    float* Of  = (float*)smem;          // 64 x 68
    float* Of2 = (float*)smem + 4352;
    __syncthreads();
    float* dst = (wr == 0) ? Of : Of2;
    #pragma unroll
    for (int ni = 0; ni < 2; ++ni)
      #pragma unroll
      for (int dj = 0; dj < 4; ++dj)
        #pragma unroll
        for (int r = 0; r < 4; ++r)
          dst[(wc * 32 + ni * 16 + lg * 4 + r) * 68 + dj * 16 + l15] = oacc[half][ni][dj][r];
    __syncthreads();
    {
      int row = tid >> 2, c0 = (tid & 3) * 16;
      float* gp = out + ((size_t)(b * 1024) + ith * 64 + row) * 1024 + h * 64 + c0;
      const float* s1p = Of  + row * 68 + c0;
      const float* s2p = Of2 + row * 68 + c0;
      #pragma unroll
      for (int c = 0; c < 4; ++c){
        float4 x = *(const float4*)(s1p + c * 4);
        float4 y = *(const float4*)(s2p + c * 4);
        *(float4*)(gp + c * 4) = make_float4(x.x + y.x, x.y + y.y, x.z + y.z, x.w + y.w);
      }
    }
  }
}

extern "C" void kernel_launch(void* const* d_in, const int* in_sizes, int n_in,
                              void* d_out, int out_size, void* d_ws, size_t ws_size,
                              hipStream_t stream) {
  (void)in_sizes; (void)n_in; (void)out_size; (void)ws_size;
  const float* X    = (const float*)d_in[0];
  const float* mask = (const float*)d_in[1];
  const float* Wq   = (const float*)d_in[2];
  const float* bq   = (const float*)d_in[3];
  const float* Wk   = (const float*)d_in[4];
  const float* bk   = (const float*)d_in[5];
  const float* Wv   = (const float*)d_in[6];
  const float* bv   = (const float*)d_in[7];
  const float* Aq   = (const float*)d_in[8];
  const float* Bq   = (const float*)d_in[9];
  const float* Ak   = (const float*)d_in[10];
  const float* Bk   = (const float*)d_in[11];
  const float* Av   = (const float*)d_in[12];
  const float* Bv   = (const float*)d_in[13];
  float* out = (float*)d_out;

  uint16_t* Xb   = (uint16_t*)d_ws;                        // 8 MB
  uint16_t* Weff = Xb + (size_t)4096 * 1024;               // 6 MB  [3072][1024]
  uint16_t* QKV  = Weff + (size_t)3 * 1024 * 1024;         // 24 MB [4096][3072]
  uint16_t* Vp   = QKV + (size_t)4096 * 3072;              // 8 MB  [64][64][1024]
  float*    csum = (float*)(Vp + (size_t)64 * 64 * 1024);  // 256 KB

  k_xcast<<<2048, 256, 0, stream>>>(X, Xb);
  k_zero<<<64, 256, 0, stream>>>(csum);
  k_weff<<<dim3(4096, 3), 256, 0, stream>>>(Wq, Aq, Bq, Wk, Ak, Bk, Wv, Av, Bv, Weff);
  k_gemm<<<768, 256, 0, stream>>>(Xb, Weff, bq, bk, bv, QKV);
  k_colsum<<<1024, 256, 0, stream>>>(QKV, csum);
  k_vprep<<<512, 256, 0, stream>>>(QKV, csum, mask, Vp);
  k_attnout<<<512, 256, 0, stream>>>(QKV, Vp, out);
}

// Round 10
// 106.081 us; speedup vs baseline: 1.3377x; 1.2125x over previous
//
#include <hip/hip_runtime.h>
#include <stdint.h>

typedef __bf16 v8bf __attribute__((ext_vector_type(8)));
typedef float  v4f  __attribute__((ext_vector_type(4)));

__device__ __forceinline__ uint16_t f2bf(float f){
  union { float f; uint32_t u; } v; v.f = f;
  uint32_t r = v.u + 0x7FFFu + ((v.u >> 16) & 1u);
  return (uint16_t)(r >> 16);
}
__device__ __forceinline__ float bf2f(uint16_t u){
  union { uint32_t u; float f; } v; v.u = ((uint32_t)u) << 16; return v.f;
}
__device__ __forceinline__ v4f vzero(){ v4f z = {0.f,0.f,0.f,0.f}; return z; }

// async global->LDS, 16B per lane; LDS dest is wave-uniform base + lane*16
__device__ __forceinline__ void gld16(const uint16_t* __restrict__ g, uint16_t* l){
  __builtin_amdgcn_global_load_lds((const __attribute__((address_space(1))) void*)g,
                                   (__attribute__((address_space(3))) void*)l, 16, 0, 0);
}

// ---- 64x64 bf16 tile staging, LDS row stride 72 (colsum) ----
__device__ __forceinline__ void ld64(uint4 r[2], const uint16_t* __restrict__ g, int ldg, int tid){
  int row = tid >> 2, c = (tid & 3) * 16;
  r[0] = *(const uint4*)(g + (size_t)row * ldg + c);
  r[1] = *(const uint4*)(g + (size_t)row * ldg + c + 8);
}
__device__ __forceinline__ void st64(uint16_t* __restrict__ s, const uint4 r[2], int tid){
  int row = tid >> 2, c = (tid & 3) * 16;
  *(uint4*)(s + row * 72 + c) = r[0];
  *(uint4*)(s + row * 72 + c + 8) = r[1];
}
__device__ __forceinline__ void stage64(uint16_t* s, const uint16_t* g, int ldg, int tid){
  uint4 r[2]; ld64(r, g, ldg, tid); st64(s, r, tid);
}

// ---- stride-64 stores: swizzled (chunk ^= row&7) and linear ----
__device__ __forceinline__ void st64s(uint16_t* __restrict__ s, const uint4 r[2], int tid){
  int row = tid >> 2, c0 = (tid & 3) * 2, sw = row & 7;
  *(uint4*)(s + row * 64 + ((c0 ^ sw) * 8))       = r[0];
  *(uint4*)(s + row * 64 + (((c0 + 1) ^ sw) * 8)) = r[1];
}
__device__ __forceinline__ void st64lin(uint16_t* __restrict__ s, const uint4 r[2], int tid){
  int row = tid >> 2, c = (tid & 3) * 16;
  *(uint4*)(s + row * 64 + c) = r[0];
  *(uint4*)(s + row * 64 + c + 8) = r[1];
}
__device__ __forceinline__ void stage64s(uint16_t* s, const uint16_t* g, int ldg, int tid){
  uint4 r[2]; ld64(r, g, ldg, tid); st64s(s, r, tid);
}

// ---------------- prep ----------------
__global__ void k_xcast(const float* __restrict__ X, uint16_t* __restrict__ Xb){
  int i = (blockIdx.x * 256 + threadIdx.x) * 8;
  float4 a = *(const float4*)(X + i);
  float4 b = *(const float4*)(X + i + 4);
  union { uint16_t h[8]; uint4 v; } o;
  o.h[0]=f2bf(a.x); o.h[1]=f2bf(a.y); o.h[2]=f2bf(a.z); o.h[3]=f2bf(a.w);
  o.h[4]=f2bf(b.x); o.h[5]=f2bf(b.y); o.h[6]=f2bf(b.z); o.h[7]=f2bf(b.w);
  *(uint4*)(Xb + i) = o.v;
}

__global__ void k_zero(float* __restrict__ p){
  int i = (blockIdx.x * 256 + threadIdx.x) * 4;
  *(float4*)(p + i) = make_float4(0.f, 0.f, 0.f, 0.f);
}

__global__ void k_weff(const float* __restrict__ Wq, const float* __restrict__ Aq, const float* __restrict__ Bq,
                       const float* __restrict__ Wk, const float* __restrict__ Ak, const float* __restrict__ Bk,
                       const float* __restrict__ Wv, const float* __restrict__ Av, const float* __restrict__ Bv,
                       uint16_t* __restrict__ Wo){
  int y = blockIdx.y;
  const float* W  = (y == 0) ? Wq : (y == 1) ? Wk : Wv;
  const float* A  = (y == 0) ? Aq : (y == 1) ? Ak : Av;
  const float* Bm = (y == 0) ? Bq : (y == 1) ? Bk : Bv;
  int idx = blockIdx.x * 256 + threadIdx.x;
  int f = idx >> 10, k = idx & 1023;
  float acc = W[idx];
  #pragma unroll
  for (int r = 0; r < 16; ++r) acc += Bm[f * 16 + r] * A[r * 1024 + k];
  Wo[(size_t)y * 1048576 + idx] = f2bf(acc);
}

// ---------------- fused QKV projection GEMM (m97 structure + XOR swizzle) ----------------
__global__ __launch_bounds__(256, 4)
void k_gemm(const uint16_t* __restrict__ Ag, const uint16_t* __restrict__ Bg,
            const float* __restrict__ qb, const float* __restrict__ kb,
            const float* __restrict__ vb, uint16_t* __restrict__ Cg){
  __shared__ __align__(16) uint16_t smem[16896];
  uint16_t* As = smem;
  uint16_t* Bs = smem + 8192;
  int tid = threadIdx.x, lane = tid & 63, wid = tid >> 6;
  int l15 = lane & 15, lg = lane >> 4;
  int wr = wid >> 1, wc = wid & 1;
  int bid = blockIdx.x, xcd = bid & 7, idx = bid >> 3;
  int nb = xcd * 96 + idx;
  int mt = nb / 24, nt = nb - mt * 24;
  int m0 = mt * 128, n0 = nt * 128;

  int lr  = lane >> 3;
  int lcs = (((lane & 7) ^ lr)) * 8;
  const uint16_t* Abase = Ag + (size_t)(m0 + wid * 32 + lr) * 1024 + lcs;
  const uint16_t* Bbase = Bg + (size_t)(n0 + wid * 32 + lr) * 1024 + lcs;
  uint16_t* Alds = As + wid * 32 * 64;
  uint16_t* Blds = Bs + wid * 32 * 64;

  int sw = l15 & 7;

  v4f acc[4][4];
  #pragma unroll
  for (int a = 0; a < 4; ++a)
    #pragma unroll
    for (int c = 0; c < 4; ++c) acc[a][c] = vzero();

  for (int kk = 0; kk < 1024; kk += 64){
    __syncthreads();
    #pragma unroll
    for (int i = 0; i < 4; ++i){
      gld16(Abase + (size_t)(i * 8) * 1024 + kk, Alds + i * 8 * 64);
      gld16(Bbase + (size_t)(i * 8) * 1024 + kk, Blds + i * 8 * 64);
    }
    __syncthreads();
    #pragma unroll
    for (int kc = 0; kc < 2; ++kc){
      v8bf af[4], bfr[4];
      int cs = ((kc * 4 + lg) ^ sw) * 8;
      #pragma unroll
      for (int mi = 0; mi < 4; ++mi)
        af[mi] = *(const v8bf*)(As + (wr * 64 + mi * 16 + l15) * 64 + cs);
      #pragma unroll
      for (int nj = 0; nj < 4; ++nj)
        bfr[nj] = *(const v8bf*)(Bs + (wc * 64 + nj * 16 + l15) * 64 + cs);
      #pragma unroll
      for (int mi = 0; mi < 4; ++mi)
        #pragma unroll
        for (int nj = 0; nj < 4; ++nj)
          acc[mi][nj] = __builtin_amdgcn_mfma_f32_16x16x32_bf16(af[mi], bfr[nj], acc[mi][nj], 0, 0, 0);
    }
  }
  __syncthreads();
  uint16_t* Ct = smem;
  #pragma unroll
  for (int nj = 0; nj < 4; ++nj){
    int n = n0 + wc * 64 + nj * 16 + l15;
    float bv_ = (n < 1024) ? qb[n] : (n < 2048) ? kb[n - 1024] : vb[n - 2048];
    #pragma unroll
    for (int mi = 0; mi < 4; ++mi)
      #pragma unroll
      for (int r = 0; r < 4; ++r){
        int ml = wr * 64 + mi * 16 + lg * 4 + r;
        Ct[ml * 132 + wc * 64 + nj * 16 + l15] = f2bf(acc[mi][nj][r] + bv_);
      }
  }
  __syncthreads();
  {
    int row = tid >> 1;
    int c0  = (tid & 1) * 64;
    uint16_t* gp = Cg + (size_t)(m0 + row) * 3072 + n0 + c0;
    const uint16_t* sp = Ct + row * 132 + c0;
    #pragma unroll
    for (int c = 0; c < 8; ++c)
      *(uint4*)(gp + c * 8) = *(const uint4*)(sp + c * 8);
  }
}

// ---------------- k_score: compute S-tiles once; exp; csum; dump P tiles ----------------
// grid 1024 = (xcd, slot, pr, ph). Orientation A=K (rows j), B=Q (rows i):
// frag col(l15)=i, row(lg*4+r)=j -> j-contiguous pairs pack directly into P A-frag layout.
__global__ __launch_bounds__(256, 4)
void k_score(const uint16_t* __restrict__ QKVg, float* __restrict__ csum,
             uint16_t* __restrict__ Pws){
  __shared__ __align__(16) uint16_t Ka[4096], Kb2[4096], Qs[4096], PsA[4096], PsB[4096];
  int tid = threadIdx.x, lane = tid & 63, wid = tid >> 6;
  int l15 = lane & 15, lg = lane >> 4;
  int wr = wid >> 1, wc = wid & 1;
  int sw = l15 & 7;
  int bid = blockIdx.x, xcd = bid & 7, idx = bid >> 3;
  int bh = xcd * 8 + (idx & 7);
  int rest = idx >> 3;
  int pr = rest & 7, ph = rest >> 3;
  int b = bh >> 4, h = bh & 15;
  int jtA = pr, jtB = 15 - pr;
  const uint16_t* Qb = QKVg + (size_t)b * 1024 * 3072 + h * 64;
  const uint16_t* Kb = QKVg + (size_t)b * 1024 * 3072 + 1024 + h * 64;
  uint16_t* Pbh = Pws + (size_t)bh * 557056;

  int lr  = lane >> 3;
  int lcs = ((lane & 7) ^ lr) * 8;           // pre-swizzled source chunk
  {                                           // stage K tiles once (swizzled image, gld16)
    const uint16_t* sA = Kb + (size_t)(jtA * 64 + wid * 16 + lr) * 3072 + lcs;
    const uint16_t* sB = Kb + (size_t)(jtB * 64 + wid * 16 + lr) * 3072 + lcs;
    gld16(sA, Ka + wid * 16 * 64);
    gld16(sA + (size_t)8 * 3072, Ka + (wid * 16 + 8) * 64);
    gld16(sB, Kb2 + wid * 16 * 64);
    gld16(sB + (size_t)8 * 3072, Kb2 + (wid * 16 + 8) * 64);
  }
  int it0 = jtA + ph;
  v4f cpA[2] = {vzero(), vzero()}, cpB[2] = {vzero(), vzero()};
  for (int it = it0; it < 16; it += 2){
    __syncthreads();                          // prev dumps done / Qs free
    {
      const uint16_t* sQ = Qb + (size_t)(it * 64 + wid * 16 + lr) * 3072 + lcs;
      gld16(sQ, Qs + wid * 16 * 64);
      gld16(sQ + (size_t)8 * 3072, Qs + (wid * 16 + 8) * 64);
    }
    __syncthreads();                          // Qs (and first-iter K) ready
    bool doB = (it >= jtB);
    v4f sa[2][2], sb[2][2];
    #pragma unroll
    for (int a = 0; a < 2; ++a)
      #pragma unroll
      for (int c = 0; c < 2; ++c){ sa[a][c] = vzero(); sb[a][c] = vzero(); }
    #pragma unroll
    for (int kc = 0; kc < 2; ++kc){
      int cs = ((kc * 4 + lg) ^ sw) * 8;
      v8bf aq[2], k1[2], k2[2];
      #pragma unroll
      for (int ni = 0; ni < 2; ++ni)
        aq[ni] = *(const v8bf*)(Qs + (wc * 32 + ni * 16 + l15) * 64 + cs);
      #pragma unroll
      for (int mj = 0; mj < 2; ++mj)
        k1[mj] = *(const v8bf*)(Ka + (wr * 32 + mj * 16 + l15) * 64 + cs);
      __builtin_amdgcn_s_setprio(1);
      #pragma unroll
      for (int mj = 0; mj < 2; ++mj)
        #pragma unroll
        for (int ni = 0; ni < 2; ++ni)
          sa[mj][ni] = __builtin_amdgcn_mfma_f32_16x16x32_bf16(k1[mj], aq[ni], sa[mj][ni], 0, 0, 0);
      __builtin_amdgcn_s_setprio(0);
      if (doB){
        #pragma unroll
        for (int mj = 0; mj < 2; ++mj)
          k2[mj] = *(const v8bf*)(Kb2 + (wr * 32 + mj * 16 + l15) * 64 + cs);
        __builtin_amdgcn_s_setprio(1);
        #pragma unroll
        for (int mj = 0; mj < 2; ++mj)
          #pragma unroll
          for (int ni = 0; ni < 2; ++ni)
            sb[mj][ni] = __builtin_amdgcn_mfma_f32_16x16x32_bf16(k2[mj], aq[ni], sb[mj][ni], 0, 0, 0);
        __builtin_amdgcn_s_setprio(0);
      }
    }
    bool diagA = (it == jtA), diagB = (it == jtB);
    #pragma unroll
    for (int mj = 0; mj < 2; ++mj)
      #pragma unroll
      for (int ni = 0; ni < 2; ++ni){
        int iL = wc * 32 + ni * 16 + l15;
        int jb = wr * 32 + mj * 16 + lg * 4;
        {
          float e0 = (!diagA || jb + 0 <= iL) ? __expf(sa[mj][ni][0] * 0.03125f) : 0.f;
          float e1 = (!diagA || jb + 1 <= iL) ? __expf(sa[mj][ni][1] * 0.03125f) : 0.f;
          float e2 = (!diagA || jb + 2 <= iL) ? __expf(sa[mj][ni][2] * 0.03125f) : 0.f;
          float e3 = (!diagA || jb + 3 <= iL) ? __expf(sa[mj][ni][3] * 0.03125f) : 0.f;
          v4f e4 = {e0, e1, e2, e3};
          cpA[mj] += e4;
          uint2 pk;
          pk.x = (uint32_t)f2bf(e0) | ((uint32_t)f2bf(e1) << 16);
          pk.y = (uint32_t)f2bf(e2) | ((uint32_t)f2bf(e3) << 16);
          *(uint2*)(PsA + iL * 64 + (((jb >> 3) ^ (iL & 7)) * 8) + (jb & 7)) = pk;
        }
        if (doB){
          float e0 = (!diagB || jb + 0 <= iL) ? __expf(sb[mj][ni][0] * 0.03125f) : 0.f;
          float e1 = (!diagB || jb + 1 <= iL) ? __expf(sb[mj][ni][1] * 0.03125f) : 0.f;
          float e2 = (!diagB || jb + 2 <= iL) ? __expf(sb[mj][ni][2] * 0.03125f) : 0.f;
          float e3 = (!diagB || jb + 3 <= iL) ? __expf(sb[mj][ni][3] * 0.03125f) : 0.f;
          v4f e4 = {e0, e1, e2, e3};
          cpB[mj] += e4;
          uint2 pk;
          pk.x = (uint32_t)f2bf(e0) | ((uint32_t)f2bf(e1) << 16);
          pk.y = (uint32_t)f2bf(e2) | ((uint32_t)f2bf(e3) << 16);
          *(uint2*)(PsB + iL * 64 + (((jb >> 3) ^ (iL & 7)) * 8) + (jb & 7)) = pk;
        }
      }
    __syncthreads();                          // Ps visible
    {
      int tri = it * (it + 1) / 2;
      uint16_t* dA = Pbh + (size_t)(tri + jtA) * 4096 + tid * 16;
      uint4 a0 = *(const uint4*)(PsA + tid * 16);
      uint4 a1 = *(const uint4*)(PsA + tid * 16 + 8);
      *(uint4*)dA = a0; *(uint4*)(dA + 8) = a1;
      if (doB){
        uint16_t* dB = Pbh + (size_t)(tri + jtB) * 4096 + tid * 16;
        uint4 b0 = *(const uint4*)(PsB + tid * 16);
        uint4 b1 = *(const uint4*)(PsB + tid * 16 + 8);
        *(uint4*)dB = b0; *(uint4*)(dB + 8) = b1;
      }
    }
  }
  // csum: reduce over l15 within each lg group, then atomicAdd
  #pragma unroll
  for (int mj = 0; mj < 2; ++mj)
    #pragma unroll
    for (int m = 1; m <= 8; m <<= 1)
      #pragma unroll
      for (int r = 0; r < 4; ++r){
        cpA[mj][r] += __shfl_xor(cpA[mj][r], m, 64);
        cpB[mj][r] += __shfl_xor(cpB[mj][r], m, 64);
      }
  if (l15 == 0){
    #pragma unroll
    for (int mj = 0; mj < 2; ++mj)
      #pragma unroll
      for (int r = 0; r < 4; ++r){
        int jo = wr * 32 + mj * 16 + lg * 4 + r;
        atomicAdd(&csum[(size_t)bh * 1024 + jtA * 64 + jo], cpA[mj][r]);
        atomicAdd(&csum[(size_t)bh * 1024 + jtB * 64 + jo], cpB[mj][r]);
      }
  }
}

// ---------------- V' = V * mask/colsum, transposed + chunk-swizzled [bh][64 d][1024 j] ----------------
__global__ __launch_bounds__(256)
void k_vprep(const uint16_t* __restrict__ QKVg, const float* __restrict__ csum,
             const float* __restrict__ mask, uint16_t* __restrict__ Vp){
  __shared__ __align__(16) uint16_t Vs[128 * 72];
  __shared__ float scb[128];
  int tid = threadIdx.x;
  int bid = blockIdx.x, xcd = bid & 7, idx = bid >> 3;
  int bh = xcd * 8 + (idx & 7);
  int jt = idx >> 3;
  int b = bh >> 4, h = bh & 15;
  int j0 = jt * 128;
  stage64(Vs,           QKVg + ((size_t)(b * 1024 + j0)) * 3072 + 2048 + h * 64, 3072, tid);
  stage64(Vs + 64 * 72, QKVg + ((size_t)(b * 1024 + j0 + 64)) * 3072 + 2048 + h * 64, 3072, tid);
  if (tid < 128) scb[tid] = mask[b * 1024 + j0 + tid] / csum[(size_t)bh * 1024 + j0 + tid];
  __syncthreads();
  int d = tid >> 2, jc = (tid & 3) * 32;
  #pragma unroll
  for (int g8 = 0; g8 < 4; ++g8){
    union { uint16_t h[8]; uint4 v; } o;
    #pragma unroll
    for (int e = 0; e < 8; ++e){
      int j = jc + g8 * 8 + e;
      o.h[e] = f2bf(bf2f(Vs[j * 72 + d]) * scb[j]);
    }
    int jl = jc + g8 * 8;                     // within 128-block
    int wbase = jl & ~63;                     // 64-window base
    int c = (jl & 63) >> 3;                   // logical chunk in window
    int jphys = wbase + ((c ^ (d & 7)) * 8);  // swizzled position
    *(uint4*)(Vp + (size_t)bh * 65536 + (size_t)d * 1024 + j0 + jphys) = o.v;
  }
}

// ---------------- k_pv: O = P @ V' (pure streaming triangular GEMM) ----------------
// grid 1024 = (xcd, slot, it). Wave w computes O rows [w*16, w*16+16).
__global__ __launch_bounds__(256, 4)
void k_pv(const uint16_t* __restrict__ Pws, const uint16_t* __restrict__ Vp,
          float* __restrict__ out){
  __shared__ __align__(16) uint16_t smem[8704];  // Pt[0..4096) Vt[4096..8192); Of f32 alias (17408B)
  uint16_t* Pt = smem;
  uint16_t* Vt = smem + 4096;
  int tid = threadIdx.x, lane = tid & 63, l15 = lane & 15, lg = lane >> 4, wid = tid >> 6;
  int bid = blockIdx.x, xcd = bid & 7, idx = bid >> 3;
  int bh = xcd * 8 + (idx & 7);
  int it = idx >> 3;
  int b = bh >> 4, h = bh & 15;
  const uint16_t* Pbh = Pws + (size_t)bh * 557056 + (size_t)(it * (it + 1) / 2) * 4096;
  const uint16_t* Vb  = Vp + (size_t)bh * 65536;
  v4f oacc[4];
  #pragma unroll
  for (int c = 0; c < 4; ++c) oacc[c] = vzero();

  for (int jt = 0; jt <= it; ++jt){
    __syncthreads();                           // prev compute done
    {
      const uint16_t* ps = Pbh + (size_t)jt * 4096;
      gld16(ps + wid * 512 + lane * 8,        Pt + wid * 512);
      gld16(ps + 2048 + wid * 512 + lane * 8, Pt + 2048 + wid * 512);
      const uint16_t* vs = Vb + (size_t)jt * 64;
      gld16(vs + (size_t)(wid * 8 + (lane >> 3)) * 1024 + (lane & 7) * 8,        Vt + wid * 512);
      gld16(vs + (size_t)(32 + wid * 8 + (lane >> 3)) * 1024 + (lane & 7) * 8,   Vt + 2048 + wid * 512);
    }
    __syncthreads();                           // tiles ready
    #pragma unroll
    for (int kc = 0; kc < 2; ++kc){
      int cs = ((kc * 4 + lg) ^ (l15 & 7)) * 8;
      v8bf pa = *(const v8bf*)(Pt + (wid * 16 + l15) * 64 + cs);
      v8bf vb_[4];
      #pragma unroll
      for (int dj = 0; dj < 4; ++dj)
        vb_[dj] = *(const v8bf*)(Vt + (dj * 16 + l15) * 64 + cs);
      __builtin_amdgcn_s_setprio(1);
      #pragma unroll
      for (int dj = 0; dj < 4; ++dj)
        oacc[dj] = __builtin_amdgcn_mfma_f32_16x16x32_bf16(pa, vb_[dj], oacc[dj], 0, 0, 0);
      __builtin_amdgcn_s_setprio(0);
    }
  }
  // epilogue: LDS-staged coalesced f32 store
  __syncthreads();
  float* Of = (float*)smem;                    // 64 x 68
  #pragma unroll
  for (int dj = 0; dj < 4; ++dj)
    #pragma unroll
    for (int r = 0; r < 4; ++r)
      Of[(wid * 16 + lg * 4 + r) * 68 + dj * 16 + l15] = oacc[dj][r];
  __syncthreads();
  {
    int row = tid >> 2, c0 = (tid & 3) * 16;
    float* gp = out + ((size_t)(b * 1024) + it * 64 + row) * 1024 + h * 64 + c0;
    const float* sp = Of + row * 68 + c0;
    #pragma unroll
    for (int c = 0; c < 4; ++c)
      *(float4*)(gp + c * 4) = *(const float4*)(sp + c * 4);
  }
}

// ---------------- fallback pass 1: column sums (unchanged) ----------------
__global__ __launch_bounds__(256, 4)
void k_colsum(const uint16_t* __restrict__ QKVg, float* __restrict__ csum){
  __shared__ __align__(16) uint16_t Ka[64 * 72], KbS[64 * 72], Qs[64 * 72];
  __shared__ float colacc[128];
  int tid = threadIdx.x, lane = tid & 63, l15 = lane & 15, lg = lane >> 4, wid = tid >> 6;
  int wr = wid >> 1, wc = wid & 1;
  int bid = blockIdx.x, xcd = bid & 7, idx = bid >> 3;
  int bh = xcd * 8 + (idx & 7);
  int rest = idx >> 3;
  int pr = rest & 7, ph = rest >> 3;
  int b = bh >> 4, h = bh & 15;
  int jtA = pr, jtB = 15 - pr;
  const uint16_t* Qb = QKVg + (size_t)b * 1024 * 3072 + h * 64;
  const uint16_t* Kb = QKVg + (size_t)b * 1024 * 3072 + 1024 + h * 64;
  stage64(Ka,  Kb + (size_t)jtA * 64 * 3072, 3072, tid);
  stage64(KbS, Kb + (size_t)jtB * 64 * 3072, 3072, tid);
  if (tid < 128) colacc[tid] = 0.f;
  int it0 = jtA + ph;
  uint4 rq[2]; ld64(rq, Qb + (size_t)it0 * 64 * 3072, 3072, tid);
  float cpA[2] = {0.f, 0.f}, cpB[2] = {0.f, 0.f};
  for (int it = it0; it < 16; it += 2){
    __syncthreads();
    st64(Qs, rq, tid);
    __syncthreads();
    if (it + 2 < 16) ld64(rq, Qb + (size_t)(it + 2) * 64 * 3072, 3072, tid);
    bool doB = (it >= jtB);
    v4f sa[2][2], sb[2][2];
    #pragma unroll
    for (int a = 0; a < 2; ++a)
      #pragma unroll
      for (int c = 0; c < 2; ++c){ sa[a][c] = vzero(); sb[a][c] = vzero(); }
    #pragma unroll
    for (int kc = 0; kc < 2; ++kc){
      v8bf aq[2], k1[2], k2[2];
      #pragma unroll
      for (int mi = 0; mi < 2; ++mi)
        aq[mi] = *(const v8bf*)(Qs + (wr * 32 + mi * 16 + l15) * 72 + kc * 32 + lg * 8);
      #pragma unroll
      for (int nj = 0; nj < 2; ++nj)
        k1[nj] = *(const v8bf*)(Ka + (wc * 32 + nj * 16 + l15) * 72 + kc * 32 + lg * 8);
      #pragma unroll
      for (int mi = 0; mi < 2; ++mi)
        #pragma unroll
        for (int nj = 0; nj < 2; ++nj)
          sa[mi][nj] = __builtin_amdgcn_mfma_f32_16x16x32_bf16(aq[mi], k1[nj], sa[mi][nj], 0, 0, 0);
      if (doB){
        #pragma unroll
        for (int nj = 0; nj < 2; ++nj)
          k2[nj] = *(const v8bf*)(KbS + (wc * 32 + nj * 16 + l15) * 72 + kc * 32 + lg * 8);
        #pragma unroll
        for (int mi = 0; mi < 2; ++mi)
          #pragma unroll
          for (int nj = 0; nj < 2; ++nj)
            sb[mi][nj] = __builtin_amdgcn_mfma_f32_16x16x32_bf16(aq[mi], k2[nj], sb[mi][nj], 0, 0, 0);
      }
    }
    #pragma unroll
    for (int mi = 0; mi < 2; ++mi)
      #pragma unroll
      for (int nj = 0; nj < 2; ++nj)
        #pragma unroll
        for (int r = 0; r < 4; ++r){
          int il = wr * 32 + mi * 16 + lg * 4 + r;
          int jl = wc * 32 + nj * 16 + l15;
          if (it > jtA || il >= jl) cpA[nj] += __expf(sa[mi][nj][r] * 0.03125f);
          if (doB && (it > jtB || il >= jl)) cpB[nj] += __expf(sb[mi][nj][r] * 0.03125f);
        }
  }
  #pragma unroll
  for (int nj = 0; nj < 2; ++nj){
    float v = cpA[nj];
    v += __shfl_xor(v, 16, 64); v += __shfl_xor(v, 32, 64);
    if (lane < 16) atomicAdd(&colacc[wc * 32 + nj * 16 + l15], v);
    float w = cpB[nj];
    w += __shfl_xor(w, 16, 64); w += __shfl_xor(w, 32, 64);
    if (lane < 16) atomicAdd(&colacc[64 + wc * 32 + nj * 16 + l15], w);
  }
  __syncthreads();
  if (tid < 64)       atomicAdd(&csum[(size_t)bh * 1024 + jtA * 64 + tid], colacc[tid]);
  else if (tid < 128) atomicAdd(&csum[(size_t)bh * 1024 + jtB * 64 + (tid - 64)], colacc[tid]);
}

// ---------------- fallback pass 2 (r9 register-P; Vt staged linear since Vp pre-swizzled) ----------------
__global__ __launch_bounds__(256, 2)
void k_attnout(const uint16_t* __restrict__ QKVg, const uint16_t* __restrict__ Vp,
               float* __restrict__ out){
  __shared__ __align__(16) uint16_t smem[24576];
  uint16_t* Qs = smem;
  uint16_t* Ks = smem + 8192;
  uint16_t* Vt = smem + 12288;
  int tid = threadIdx.x, lane = tid & 63, l15 = lane & 15, lg = lane >> 4, wid = tid >> 6;
  int wr = wid >> 1, wc = wid & 1;
  int sw = l15 & 7;
  int bid = blockIdx.x, xcd = bid & 7, idx = bid >> 3;
  int bh = xcd * 8 + (idx & 7);
  int p4 = idx >> 3; int pr = (p4 < 4) ? p4 : 11 - p4;
  int b = bh >> 4, h = bh & 15;
  int itA = pr, itB = 15 - pr;
  const uint16_t* Qb = QKVg + (size_t)b * 1024 * 3072 + h * 64;
  const uint16_t* Kb = QKVg + (size_t)b * 1024 * 3072 + 1024 + h * 64;
  const uint16_t* Vb = Vp + (size_t)bh * 65536;
  stage64s(Qs,           Qb + (size_t)itA * 64 * 3072, 3072, tid);
  stage64s(Qs + 64 * 64, Qb + (size_t)itB * 64 * 3072, 3072, tid);
  uint4 rk[2], rv[2];
  ld64(rk, Kb, 3072, tid);
  ld64(rv, Vb, 1024, tid);
  v4f oacc[2][2][4];
  #pragma unroll
  for (int a = 0; a < 2; ++a)
    #pragma unroll
    for (int c = 0; c < 2; ++c)
      #pragma unroll
      for (int d = 0; d < 4; ++d) oacc[a][c][d] = vzero();

  for (int jt = 0; jt <= itB; ++jt){
    __syncthreads();
    st64s(Ks, rk, tid);
    st64lin(Vt, rv, tid);                    // Vp already swizzled -> linear copy
    __syncthreads();
    if (jt < itB){
      ld64(rk, Kb + (size_t)(jt + 1) * 64 * 3072, 3072, tid);
      ld64(rv, Vb + (jt + 1) * 64, 1024, tid);
    }
    v8bf ak[2][2], vbf[4];
    #pragma unroll
    for (int kc = 0; kc < 2; ++kc){
      int cs = ((kc * 4 + lg) ^ sw) * 8;
      #pragma unroll
      for (int mj = 0; mj < 2; ++mj)
        ak[kc][mj] = *(const v8bf*)(Ks + (wr * 32 + mj * 16 + l15) * 64 + cs);
    }
    {
      int csv = ((wr * 4 + lg) ^ sw) * 8;
      #pragma unroll
      for (int dj = 0; dj < 4; ++dj)
        vbf[dj] = *(const v8bf*)(Vt + (dj * 16 + l15) * 64 + csv);
    }
    #pragma unroll
    for (int half = 0; half < 2; ++half){
      int ith = half ? itB : itA;
      if (jt <= ith){
        v4f sacc[2][2];
        #pragma unroll
        for (int a = 0; a < 2; ++a)
          #pragma unroll
          for (int c = 0; c < 2; ++c) sacc[a][c] = vzero();
        #pragma unroll
        for (int kc = 0; kc < 2; ++kc){
          v8bf aq[2];
          int cs = ((kc * 4 + lg) ^ sw) * 8;
          #pragma unroll
          for (int ni = 0; ni < 2; ++ni)
            aq[ni] = *(const v8bf*)(Qs + (half * 64 + wc * 32 + ni * 16 + l15) * 64 + cs);
          __builtin_amdgcn_s_setprio(1);
          #pragma unroll
          for (int mj = 0; mj < 2; ++mj)
            #pragma unroll
            for (int ni = 0; ni < 2; ++ni)
              sacc[mj][ni] = __builtin_amdgcn_mfma_f32_16x16x32_bf16(ak[kc][mj], aq[ni], sacc[mj][ni], 0, 0, 0);
          __builtin_amdgcn_s_setprio(0);
        }
        bool diag = (jt == ith);
        uint32_t pk[2][2][2];
        #pragma unroll
        for (int mj = 0; mj < 2; ++mj)
          #pragma unroll
          for (int ni = 0; ni < 2; ++ni){
            int iL = wc * 32 + ni * 16 + l15;
            int jb = wr * 32 + mj * 16 + lg * 4;
            float e0 = (!diag || jb + 0 <= iL) ? __expf(sacc[mj][ni][0] * 0.03125f) : 0.f;
            float e1 = (!diag || jb + 1 <= iL) ? __expf(sacc[mj][ni][1] * 0.03125f) : 0.f;
            float e2 = (!diag || jb + 2 <= iL) ? __expf(sacc[mj][ni][2] * 0.03125f) : 0.f;
            float e3 = (!diag || jb + 3 <= iL) ? __expf(sacc[mj][ni][3] * 0.03125f) : 0.f;
            pk[mj][ni][0] = (uint32_t)f2bf(e0) | ((uint32_t)f2bf(e1) << 16);
            pk[mj][ni][1] = (uint32_t)f2bf(e2) | ((uint32_t)f2bf(e3) << 16);
          }
        int s0 = ((lg & 1) * 32) + l15;
        int s1 = s0 + 16;
        bool hi = (lg >> 1) != 0;
        #pragma unroll
        for (int ni = 0; ni < 2; ++ni){
          uint32_t a0x = __shfl((int)pk[0][ni][0], s0, 64), a1x = __shfl((int)pk[1][ni][0], s0, 64);
          uint32_t a0y = __shfl((int)pk[0][ni][1], s0, 64), a1y = __shfl((int)pk[1][ni][1], s0, 64);
          uint32_t b0x = __shfl((int)pk[0][ni][0], s1, 64), b1x = __shfl((int)pk[1][ni][0], s1, 64);
          uint32_t b0y = __shfl((int)pk[0][ni][1], s1, 64), b1y = __shfl((int)pk[1][ni][1], s1, 64);
          union { uint32_t u[4]; v8bf v; } fr;
          fr.u[0] = hi ? a1x : a0x;
          fr.u[1] = hi ? a1y : a0y;
          fr.u[2] = hi ? b1x : b0x;
          fr.u[3] = hi ? b1y : b0y;
          __builtin_amdgcn_s_setprio(1);
          #pragma unroll
          for (int dj = 0; dj < 4; ++dj)
            oacc[half][ni][dj] = __builtin_amdgcn_mfma_f32_16x16x32_bf16(fr.v, vbf[dj], oacc[half][ni][dj], 0, 0, 0);
          __builtin_amdgcn_s_setprio(0);
        }
      }
    }
  }
  #pragma unroll
  for (int half = 0; half < 2; ++half){
    int ith = half ? itB : itA;
    float* Of  = (float*)smem;
    float* Of2 = (float*)smem + 4352;
    __syncthreads();
    float* dst = (wr == 0) ? Of : Of2;
    #pragma unroll
    for (int ni = 0; ni < 2; ++ni)
      #pragma unroll
      for (int dj = 0; dj < 4; ++dj)
        #pragma unroll
        for (int r = 0; r < 4; ++r)
          dst[(wc * 32 + ni * 16 + lg * 4 + r) * 68 + dj * 16 + l15] = oacc[half][ni][dj][r];
    __syncthreads();
    {
      int row = tid >> 2, c0 = (tid & 3) * 16;
      float* gp = out + ((size_t)(b * 1024) + ith * 64 + row) * 1024 + h * 64 + c0;
      const float* s1p = Of  + row * 68 + c0;
      const float* s2p = Of2 + row * 68 + c0;
      #pragma unroll
      for (int c = 0; c < 4; ++c){
        float4 x = *(const float4*)(s1p + c * 4);
        float4 y = *(const float4*)(s2p + c * 4);
        *(float4*)(gp + c * 4) = make_float4(x.x + y.x, x.y + y.y, x.z + y.z, x.w + y.w);
      }
    }
  }
}

extern "C" void kernel_launch(void* const* d_in, const int* in_sizes, int n_in,
                              void* d_out, int out_size, void* d_ws, size_t ws_size,
                              hipStream_t stream) {
  (void)in_sizes; (void)n_in; (void)out_size;
  const float* X    = (const float*)d_in[0];
  const float* mask = (const float*)d_in[1];
  const float* Wq   = (const float*)d_in[2];
  const float* bq   = (const float*)d_in[3];
  const float* Wk   = (const float*)d_in[4];
  const float* bk   = (const float*)d_in[5];
  const float* Wv   = (const float*)d_in[6];
  const float* bv   = (const float*)d_in[7];
  const float* Aq   = (const float*)d_in[8];
  const float* Bq   = (const float*)d_in[9];
  const float* Ak   = (const float*)d_in[10];
  const float* Bk   = (const float*)d_in[11];
  const float* Av   = (const float*)d_in[12];
  const float* Bv   = (const float*)d_in[13];
  float* out = (float*)d_out;

  uint16_t* Xb   = (uint16_t*)d_ws;                        // 8 MB
  uint16_t* Weff = Xb + (size_t)4096 * 1024;               // 6 MB
  uint16_t* QKV  = Weff + (size_t)3 * 1024 * 1024;         // 24 MB
  uint16_t* Vp   = QKV + (size_t)4096 * 3072;              // 8 MB
  float*    csum = (float*)(Vp + (size_t)64 * 64 * 1024);  // 256 KB
  uint16_t* Pws  = (uint16_t*)((char*)d_ws + 48496640ULL); // 68 MB P tiles
  const size_t need = 48496640ULL + 71303168ULL;           // ~114.3 MB

  k_xcast<<<2048, 256, 0, stream>>>(X, Xb);
  k_zero<<<64, 256, 0, stream>>>(csum);
  k_weff<<<dim3(4096, 3), 256, 0, stream>>>(Wq, Aq, Bq, Wk, Ak, Bk, Wv, Av, Bv, Weff);
  k_gemm<<<768, 256, 0, stream>>>(Xb, Weff, bq, bk, bv, QKV);
  if (ws_size >= need){
    k_score<<<1024, 256, 0, stream>>>(QKV, csum, Pws);
    k_vprep<<<512, 256, 0, stream>>>(QKV, csum, mask, Vp);
    k_pv<<<1024, 256, 0, stream>>>(Pws, Vp, out);
  } else {
    k_colsum<<<1024, 256, 0, stream>>>(QKV, csum);
    k_vprep<<<512, 256, 0, stream>>>(QKV, csum, mask, Vp);
    k_attnout<<<512, 256, 0, stream>>>(QKV, Vp, out);
  }
}